// Round 7
// baseline (107.606 us; speedup 1.0000x reference)
//
#include <hip/hip_runtime.h>
#include <math.h>

// FreqEmbedding: seq [16,512,64] f32 -> out [16,512,65,64] f32
// reflect-pad(64) -> hanning(128) frames -> rfft(128) -> complex standardize
// over (L,F) per (B,C) -> abs.
//
// Pass A (reduce): NO FFT — Parseval + symmetry identities (4 dot products).
// Pass B (write): monolithic 64-pt FFT per thread (lowest total VALU), ONE
//   compact code body: per-wave LDS table of reflect byte-offsets replaces
//   the FAST/reflect dual-path (round-4's ~2x code size was thrashing the
//   32KB I$ -> 33% VALUBusy). Round-6 lane-pair split proved 2x-work
//   VALU-bound (85us @ 64% busy) -> reverted to monolithic.

#define B_ 16
#define L_ 512
#define C_ 64
#define W_ 128
#define F_ 65
#define NLF (L_ * F_)  // 33280

// ---------- compile-time trig tables (fold to VALU literals) ----------
constexpr double kPI = 3.14159265358979323846;

constexpr double csin_(double x) {
  while (x > kPI) x -= 2.0 * kPI;
  while (x < -kPI) x += 2.0 * kPI;
  double t = x, s = x, x2 = x * x;
  for (int i = 1; i <= 24; ++i) {
    t *= -x2 / ((2.0 * i) * (2.0 * i + 1.0));
    s += t;
  }
  return s;
}
constexpr double ccos_(double x) { return csin_(kPI / 2.0 - x); }

constexpr int bitrev6(int n) {
  int r = 0;
  for (int i = 0; i < 6; ++i) r |= ((n >> i) & 1) << (5 - i);
  return r;
}

struct Tables {
  float win[128];         // hanning w_n
  float walt[128];        // (-1)^n w_n
  float w2[128];          // w_n^2
  float wg[128];          // w_n * G_n
  float twr[32], twi[32]; // exp(-2*pi*i*j/64)
  float cur[32], cui[32]; // exp(-2*pi*i*k/128), k=0..31
  constexpr Tables() : win(), walt(), w2(), wg(), twr(), twi(), cur(), cui() {
    for (int n = 0; n < 128; ++n) {
      const double wd = 0.5 - 0.5 * ccos_(2.0 * kPI * n / 127.0);
      win[n] = (float)wd;
      walt[n] = (n & 1) ? (float)(-wd) : (float)wd;
      w2[n] = (float)(wd * wd);
      if (n == 0) {
        wg[n] = 0.0f;
      } else {
        // G_n = sin(pi n/2) * sin(65 pi n/128) / sin(pi n/128)
        const double G = csin_(kPI * n / 2.0) * csin_(65.0 * kPI * n / 128.0) /
                         csin_(kPI * n / 128.0);
        wg[n] = (float)(wd * G);
      }
    }
    for (int j = 0; j < 32; ++j) {
      twr[j] = (float)ccos_(2.0 * kPI * j / 64.0);
      twi[j] = (float)(-csin_(2.0 * kPI * j / 64.0));
    }
    for (int k = 0; k < 32; ++k) {
      cur[k] = (float)ccos_(2.0 * kPI * k / 128.0);
      cui[k] = (float)(-csin_(2.0 * kPI * k / 128.0));
    }
  }
};
constexpr Tables TBL{};

// branchless reflect into [0,512): for t in [-64, 575]
//   refl(t) = min(max(t,-t), 1022 - max(t,-t))   (3 VALU)
__device__ __forceinline__ int refl(int t) {
  const int a = max(t, -t);
  return min(a, 1022 - a);
}

__device__ __forceinline__ float fast_sqrt(float x) {
  float r;
  asm("v_sqrt_f32 %0, %1" : "=v"(r) : "v"(x));
  return r;
}

__device__ __forceinline__ float ldg_off(const float* __restrict__ base, int byte_off) {
  return *reinterpret_cast<const float*>(
      reinterpret_cast<const char*>(base) + byte_off);
}

// ---------------- Pass A: Parseval reduce (unchanged, proven) ----------------
__global__ void __launch_bounds__(256)
fe_reduce_kernel(const float* __restrict__ seq, float* __restrict__ acc) {
  const int p = blockIdx.x * 4 + (threadIdx.x >> 6);
  const int b = __builtin_amdgcn_readfirstlane(p >> 9);
  const int l = __builtin_amdgcn_readfirstlane(p & (L_ - 1));
  const int c = threadIdx.x & 63;

  const float* base = seq + ((size_t)b * L_) * C_ + c;

  float x0 = 0.f, x64 = 0.f, p2 = 0.f, d2 = 0.f;
#pragma unroll
  for (int n = 0; n < 128; ++n) {
    const int t = refl(l + n - 64);
    const float v = base[(size_t)t * C_];
    x0 += TBL.win[n] * v;
    x64 += TBL.walt[n] * v;
    const float wv = TBL.w2[n] * v;
    p2 += wv * v;
    d2 += TBL.wg[n] * v;
  }

  const float sre = 0.5f * (x0 + x64);
  const float sim = -d2;
  const float ssq = 64.0f * p2 + 0.5f * (x0 * x0 + x64 * x64);

  __shared__ float red[3][256];
  const int tid = threadIdx.x;
  red[0][tid] = sre;
  red[1][tid] = sim;
  red[2][tid] = ssq;
  __syncthreads();
  if (tid < 64) {
    const float a0 = red[0][tid] + red[0][tid + 64] + red[0][tid + 128] + red[0][tid + 192];
    const float a1 = red[1][tid] + red[1][tid + 64] + red[1][tid + 128] + red[1][tid + 192];
    const float a2 = red[2][tid] + red[2][tid + 64] + red[2][tid + 128] + red[2][tid + 192];
    const int g = b * C_ + tid;
    unsafeAtomicAdd(&acc[g], a0);
    unsafeAtomicAdd(&acc[1024 + g], a1);
    unsafeAtomicAdd(&acc[2048 + g], a2);
  }
}

// ---------------- Pass B: monolithic FFT + write, single body ----------------
__global__ void __launch_bounds__(256, 3)
fe_write_kernel(const float* __restrict__ seq, const float* __restrict__ acc,
                float* __restrict__ out) {
  __shared__ int tab[4][128];  // per-wave reflect byte-offset table

  const int tid = threadIdx.x;
  const int wv = tid >> 6;     // wave id within block
  const int lane = tid & 63;
  const int p = blockIdx.x * 4 + wv;
  const int b = __builtin_amdgcn_readfirstlane(p >> 9);
  const int l = __builtin_amdgcn_readfirstlane(p & (L_ - 1));
  const int c = lane;

  // build this wave's table (same-wave ds ordering; no __syncthreads needed)
  tab[wv][lane]      = refl(l + lane - 64) << 8;  // * C_ * 4 bytes
  tab[wv][lane + 64] = refl(l + lane) << 8;

  // fused finalize: true-scale sums -> constants matching the 2x bins
  const int g = b * C_ + c;
  const float invN = 1.0f / (float)NLF;
  const float sr = acc[g] * invN;
  const float si = acc[1024 + g] * invN;
  const float qq = acc[2048 + g] * invN;
  const float var = qq - sr * sr - si * si;
  const float mr = 2.0f * sr;
  const float mi = 2.0f * si;
  const float is = 0.5f * rsqrtf(var);

  const float* sbase = seq + (size_t)b * (L_ * C_);
  const int cb = c << 2;  // channel byte offset

  // ---- load via table: zr[n] = w[2m]*s[2m], zi[n] = w[2m+1]*s[2m+1] ----
  float zr[64], zi[64];
#pragma unroll
  for (int n = 0; n < 64; ++n) {
    const int m = bitrev6(n);
    const int2 oo = *reinterpret_cast<const int2*>(&tab[wv][2 * m]);
    zr[n] = TBL.win[2 * m] * ldg_off(sbase, oo.x + cb);
    zi[n] = TBL.win[2 * m + 1] * ldg_off(sbase, oo.y + cb);
  }

  // ---- 64-point complex DIT FFT, fully unrolled, literal twiddles ----
#pragma unroll
  for (int s = 0; s < 6; ++s) {
    const int half = 1 << s;
    const int len = half << 1;
#pragma unroll
    for (int j = 0; j < half; ++j) {
      const float wr = TBL.twr[j << (5 - s)];
      const float wi = TBL.twi[j << (5 - s)];
#pragma unroll
      for (int base2 = 0; base2 < 64; base2 += len) {
        const int a = base2 + j;
        const int b2 = a + half;
        const float tr = wr * zr[b2] - wi * zi[b2];
        const float ti = wr * zi[b2] + wi * zr[b2];
        zr[b2] = zr[a] - tr;
        zi[b2] = zi[a] - ti;
        zr[a] += tr;
        zi[a] += ti;
      }
    }
  }

  float* obase = out + (((size_t)(b * L_ + l)) * F_) * C_ + c;
  auto emit = [&](int f, float Xr, float Xi) {
    const float dr = Xr - mr;
    const float di = Xi - mi;
    const float amp = fast_sqrt(__builtin_fmaf(dr, dr, di * di)) * is;
    __builtin_nontemporal_store(amp, &obase[(size_t)f * C_]);
  };

  // ---- real-FFT unpack (bins scaled 2x; compensated in mr/mi/is) ----
  emit(0, 2.0f * (zr[0] + zi[0]), 0.0f);
  emit(64, 2.0f * (zr[0] - zi[0]), 0.0f);
  emit(32, 2.0f * zr[32], -2.0f * zi[32]);
#pragma unroll
  for (int k = 1; k < 32; ++k) {
    const float cr = TBL.cur[k], ci = TBL.cui[k];
    const float Er = zr[k] + zr[64 - k];
    const float Ei = zi[k] - zi[64 - k];
    const float Or = zi[k] + zi[64 - k];
    const float Oi = zr[64 - k] - zr[k];
    const float wOr = cr * Or - ci * Oi;
    const float wOi = cr * Oi + ci * Or;
    emit(k, Er + wOr, Ei + wOi);
    emit(64 - k, Er - wOr, wOi - Ei);
  }
}

extern "C" void kernel_launch(void* const* d_in, const int* in_sizes, int n_in,
                              void* d_out, int out_size, void* d_ws, size_t ws_size,
                              hipStream_t stream) {
  const float* seq = (const float*)d_in[0];
  float* out = (float*)d_out;
  float* ws = (float*)d_ws;

  // zero the 3 accumulator arrays (3072 floats)
  hipMemsetAsync(ws, 0, 3072 * sizeof(float), stream);

  const int nblocks = (B_ * L_) / 4;  // 2048 blocks, 4 (b,l) pairs each
  fe_reduce_kernel<<<nblocks, 256, 0, stream>>>(seq, ws);
  fe_write_kernel<<<nblocks, 256, 0, stream>>>(seq, ws, out);
}

// Round 8
// 61.571 us; speedup vs baseline: 1.7477x; 1.7477x over previous
//
#include <hip/hip_runtime.h>
#include <math.h>

// FreqEmbedding: seq [16,512,64] f32 -> out [16,512,65,64] f32
// reflect-pad(64) -> hanning(128) frames -> rfft(128) -> complex standardize
// over (L,F) per (B,C) -> abs.
//
// Pass 0 (pad): materialize reflect-padded input [16,640,64] into ws (2.6 MB).
//   -> hot kernels get ONE compact body with base+imm load addressing
//      (round-7 lesson: computed per-load addresses => spill; round-4 lesson:
//       dual FAST/SLOW bodies => ~40KB code, I$ thrash, 31% VALUBusy).
// Pass A (reduce): Parseval + symmetry identities (4 dot products), on pad.
// Pass B (write): monolithic 64-pt FFT per thread, single body, nt-stores.

#define B_ 16
#define L_ 512
#define C_ 64
#define W_ 128
#define F_ 65
#define LP 640  // padded length
#define NLF (L_ * F_)  // 33280

// ---------- compile-time trig tables (fold to VALU literals) ----------
constexpr double kPI = 3.14159265358979323846;

constexpr double csin_(double x) {
  while (x > kPI) x -= 2.0 * kPI;
  while (x < -kPI) x += 2.0 * kPI;
  double t = x, s = x, x2 = x * x;
  for (int i = 1; i <= 24; ++i) {
    t *= -x2 / ((2.0 * i) * (2.0 * i + 1.0));
    s += t;
  }
  return s;
}
constexpr double ccos_(double x) { return csin_(kPI / 2.0 - x); }

constexpr int bitrev6(int n) {
  int r = 0;
  for (int i = 0; i < 6; ++i) r |= ((n >> i) & 1) << (5 - i);
  return r;
}

struct Tables {
  float win[128];         // hanning w_n
  float walt[128];        // (-1)^n w_n
  float w2[128];          // w_n^2
  float wg[128];          // w_n * G_n
  float twr[32], twi[32]; // exp(-2*pi*i*j/64)
  float cur[32], cui[32]; // exp(-2*pi*i*k/128), k=0..31
  constexpr Tables() : win(), walt(), w2(), wg(), twr(), twi(), cur(), cui() {
    for (int n = 0; n < 128; ++n) {
      const double wd = 0.5 - 0.5 * ccos_(2.0 * kPI * n / 127.0);
      win[n] = (float)wd;
      walt[n] = (n & 1) ? (float)(-wd) : (float)wd;
      w2[n] = (float)(wd * wd);
      if (n == 0) {
        wg[n] = 0.0f;
      } else {
        // G_n = sin(pi n/2) * sin(65 pi n/128) / sin(pi n/128)
        const double G = csin_(kPI * n / 2.0) * csin_(65.0 * kPI * n / 128.0) /
                         csin_(kPI * n / 128.0);
        wg[n] = (float)(wd * G);
      }
    }
    for (int j = 0; j < 32; ++j) {
      twr[j] = (float)ccos_(2.0 * kPI * j / 64.0);
      twi[j] = (float)(-csin_(2.0 * kPI * j / 64.0));
    }
    for (int k = 0; k < 32; ++k) {
      cur[k] = (float)ccos_(2.0 * kPI * k / 128.0);
      cui[k] = (float)(-csin_(2.0 * kPI * k / 128.0));
    }
  }
};
constexpr Tables TBL{};

// branchless reflect into [0,512) for t in [-64, 575]
__device__ __forceinline__ int refl(int t) {
  const int a = max(t, -t);
  return min(a, 1022 - a);
}

__device__ __forceinline__ float fast_sqrt(float x) {
  float r;
  asm("v_sqrt_f32 %0, %1" : "=v"(r) : "v"(x));
  return r;
}

// ---------------- Pass 0: materialize reflect-padded input ----------------
__global__ void __launch_bounds__(256)
fe_pad_kernel(const float* __restrict__ seq, float* __restrict__ pad) {
  const int idx = blockIdx.x * 256 + threadIdx.x;  // b*LP*C + t*C + c
  const int c = idx & 63;
  const int row = idx >> 6;  // b*LP + t
  const int b = row / LP;
  const int t = row - b * LP;
  const int s = refl(t - 64);
  pad[idx] = seq[(b * L_ + s) * C_ + c];
}

// ws layout (floats): [0..1023] sum_re, [1024..2047] sum_im, [2048..3071] sum_sq,
//                     [4096 ..] padded input [16][640][64]
// ---------------- Pass A: Parseval reduce (on padded input) ----------------
__global__ void __launch_bounds__(256)
fe_reduce_kernel(const float* __restrict__ pad, float* __restrict__ acc) {
  const int p = blockIdx.x * 4 + (threadIdx.x >> 6);
  const int b = __builtin_amdgcn_readfirstlane(p >> 9);
  const int l = __builtin_amdgcn_readfirstlane(p & (L_ - 1));
  const int c = threadIdx.x & 63;

  const float* base = pad + ((size_t)(b * LP + l)) * C_ + c;

  float x0 = 0.f, x64 = 0.f, p2 = 0.f, d2 = 0.f;
#pragma unroll
  for (int n = 0; n < 128; ++n) {
    const float v = base[n * C_];
    x0 += TBL.win[n] * v;
    x64 += TBL.walt[n] * v;
    const float wv = TBL.w2[n] * v;
    p2 += wv * v;
    d2 += TBL.wg[n] * v;
  }

  const float sre = 0.5f * (x0 + x64);
  const float sim = -d2;
  const float ssq = 64.0f * p2 + 0.5f * (x0 * x0 + x64 * x64);

  __shared__ float red[3][256];
  const int tid = threadIdx.x;
  red[0][tid] = sre;
  red[1][tid] = sim;
  red[2][tid] = ssq;
  __syncthreads();
  if (tid < 64) {
    const float a0 = red[0][tid] + red[0][tid + 64] + red[0][tid + 128] + red[0][tid + 192];
    const float a1 = red[1][tid] + red[1][tid + 64] + red[1][tid + 128] + red[1][tid + 192];
    const float a2 = red[2][tid] + red[2][tid + 64] + red[2][tid + 128] + red[2][tid + 192];
    const int g = b * C_ + tid;
    unsafeAtomicAdd(&acc[g], a0);
    unsafeAtomicAdd(&acc[1024 + g], a1);
    unsafeAtomicAdd(&acc[2048 + g], a2);
  }
}

// ---------------- Pass B: monolithic FFT + write, single compact body ----------------
__global__ void __launch_bounds__(256, 3)
fe_write_kernel(const float* __restrict__ pad, const float* __restrict__ acc,
                float* __restrict__ out) {
  const int tid = threadIdx.x;
  const int p = blockIdx.x * 4 + (tid >> 6);
  const int b = __builtin_amdgcn_readfirstlane(p >> 9);
  const int l = __builtin_amdgcn_readfirstlane(p & (L_ - 1));
  const int c = tid & 63;

  // fused finalize: true-scale sums -> constants matching the 2x bins
  const int g = b * C_ + c;
  const float invN = 1.0f / (float)NLF;
  const float sr = acc[g] * invN;
  const float si = acc[1024 + g] * invN;
  const float qq = acc[2048 + g] * invN;
  const float var = qq - sr * sr - si * si;
  const float mr = 2.0f * sr;
  const float mi = 2.0f * si;
  const float is = 0.5f * rsqrtf(var);

  const float* base = pad + ((size_t)(b * LP + l)) * C_ + c;

  // ---- load in bit-reversed order, pack even/odd, apply window ----
  float zr[64], zi[64];
#pragma unroll
  for (int n = 0; n < 64; ++n) {
    const int m = bitrev6(n);
    zr[n] = TBL.win[2 * m] * base[(2 * m) * C_];
    zi[n] = TBL.win[2 * m + 1] * base[(2 * m + 1) * C_];
  }

  // ---- 64-point complex DIT FFT, fully unrolled, literal twiddles ----
#pragma unroll
  for (int s = 0; s < 6; ++s) {
    const int half = 1 << s;
    const int len = half << 1;
#pragma unroll
    for (int j = 0; j < half; ++j) {
      const float wr = TBL.twr[j << (5 - s)];
      const float wi = TBL.twi[j << (5 - s)];
#pragma unroll
      for (int base2 = 0; base2 < 64; base2 += len) {
        const int a = base2 + j;
        const int b2 = a + half;
        const float tr = wr * zr[b2] - wi * zi[b2];
        const float ti = wr * zi[b2] + wi * zr[b2];
        zr[b2] = zr[a] - tr;
        zi[b2] = zi[a] - ti;
        zr[a] += tr;
        zi[a] += ti;
      }
    }
  }

  float* obase = out + (((size_t)(b * L_ + l)) * F_) * C_ + c;
  auto emit = [&](int f, float Xr, float Xi) {
    const float dr = Xr - mr;
    const float di = Xi - mi;
    const float amp = fast_sqrt(__builtin_fmaf(dr, dr, di * di)) * is;
    __builtin_nontemporal_store(amp, &obase[(size_t)f * C_]);
  };

  // ---- real-FFT unpack (bins scaled 2x; compensated in mr/mi/is) ----
  emit(0, 2.0f * (zr[0] + zi[0]), 0.0f);
  emit(64, 2.0f * (zr[0] - zi[0]), 0.0f);
  emit(32, 2.0f * zr[32], -2.0f * zi[32]);
#pragma unroll
  for (int k = 1; k < 32; ++k) {
    const float cr = TBL.cur[k], ci = TBL.cui[k];
    const float Er = zr[k] + zr[64 - k];
    const float Ei = zi[k] - zi[64 - k];
    const float Or = zi[k] + zi[64 - k];
    const float Oi = zr[64 - k] - zr[k];
    const float wOr = cr * Or - ci * Oi;
    const float wOi = cr * Oi + ci * Or;
    emit(k, Er + wOr, Ei + wOi);
    emit(64 - k, Er - wOr, wOi - Ei);
  }
}

extern "C" void kernel_launch(void* const* d_in, const int* in_sizes, int n_in,
                              void* d_out, int out_size, void* d_ws, size_t ws_size,
                              hipStream_t stream) {
  const float* seq = (const float*)d_in[0];
  float* out = (float*)d_out;
  float* ws = (float*)d_ws;
  float* acc = ws;          // 3072 floats
  float* pad = ws + 4096;   // 16*640*64 = 655360 floats (2.62 MB)

  hipMemsetAsync(acc, 0, 3072 * sizeof(float), stream);

  fe_pad_kernel<<<(B_ * LP * C_) / 256, 256, 0, stream>>>(seq, pad);
  const int nblocks = (B_ * L_) / 4;  // 2048 blocks, 4 (b,l) pairs each
  fe_reduce_kernel<<<nblocks, 256, 0, stream>>>(pad, ws);
  fe_write_kernel<<<nblocks, 256, 0, stream>>>(pad, ws, out);
}